// Round 1
// baseline (1192.056 us; speedup 1.0000x reference)
//
#include <hip/hip_runtime.h>
#include <cstdint>
#include <math.h>

#define EPS_BN 1e-5f
#define SLOPE 0.01f

// ---------- weight transform: w[O][I][3] -> wT[(i*3+t)*O + o] ----------
__global__ __launch_bounds__(256)
void wprep_kernel(const float* __restrict__ w, float* __restrict__ wT,
                  int CIN, int COUT)
{
    int total = CIN * 3 * COUT;
    for (int idx = blockIdx.x * 256 + threadIdx.x; idx < total;
         idx += gridDim.x * 256) {
        int o = idx % COUT;
        int r = idx / COUT;            // r = i*3 + t
        int i = r / 3, t = r - i * 3;
        wT[idx] = w[((size_t)o * CIN + i) * 3 + t];
    }
}

// ---------- fused conv1d(k=3,pad=1) + BN(eval) + LeakyReLU ----------
// tile: 64 out-channels x 64 out-positions per block, one batch.
// thread micro-tile: 4 oc x 4 pos. K staged in LDS in chunks of IC=16.
template<int CIN, int COUT, int LIN, int STRIDE, bool TRANS_OUT>
__global__ __launch_bounds__(256)
void conv_bn_lrelu(const float* __restrict__ in, const float* __restrict__ wT,
                   const float* __restrict__ bias,
                   const float* __restrict__ gg, const float* __restrict__ be,
                   const float* __restrict__ mm, const float* __restrict__ vv,
                   float* __restrict__ out)
{
    constexpr int LOUT  = LIN / STRIDE;
    constexpr int XSPAN = STRIDE * 63 + 3;       // 129 (s2) or 66 (s1)
    constexpr int XROW  = (XSPAN + 3) & ~3;      // 132 or 68 (16B-aligned rows)
    constexpr int IC    = 16;
    constexpr int NX    = 3 * STRIDE + 3;        // 9 or 6 x-values per thread

    __shared__ __align__(16) float xs[IC][XROW];
    __shared__ __align__(16) float wsh[IC * 3][64];

    const int tid = threadIdx.x;
    const int l0  = blockIdx.x * 64;
    const int o0  = blockIdx.y * 64;
    const int b   = blockIdx.z;

    const int lt = tid & 15, ot = tid >> 4;
    const int lb = lt * 4,   ob = ot * 4;

    float acc[4][4] = {};                        // [oo][ll]
    const int l0in = l0 * STRIDE - 1;
    const float* inb = in + (size_t)b * CIN * LIN;

    for (int i0 = 0; i0 < CIN; i0 += IC) {
        __syncthreads();
        // stage X chunk (with zero padding at the borders)
        for (int idx = tid; idx < IC * XSPAN; idx += 256) {
            int i = idx / XSPAN, j = idx - i * XSPAN;
            int p = l0in + j;
            float val = 0.0f;
            if (p >= 0 && p < LIN) val = inb[(size_t)(i0 + i) * LIN + p];
            xs[i][j] = val;
        }
        // stage W chunk: wsh[i*3+t][o] <- wT[(i0*3 + i*3+t)*COUT + o0+o]
        for (int idx = tid; idx < IC * 3 * 64; idx += 256) {
            int o = idx & 63, r = idx >> 6;
            wsh[r][o] = wT[(size_t)(i0 * 3 + r) * COUT + o0 + o];
        }
        __syncthreads();

        #pragma unroll
        for (int i = 0; i < IC; ++i) {
            float xr[NX];
            if (STRIDE == 2) {
                float4 a = *(const float4*)&xs[i][lb * 2];
                float4 c = *(const float4*)&xs[i][lb * 2 + 4];
                xr[0] = a.x; xr[1] = a.y; xr[2] = a.z; xr[3] = a.w;
                xr[4] = c.x; xr[5] = c.y; xr[6] = c.z; xr[7] = c.w;
                xr[8] = xs[i][lb * 2 + 8];
            } else {
                float4 a = *(const float4*)&xs[i][lb];
                xr[0] = a.x; xr[1] = a.y; xr[2] = a.z; xr[3] = a.w;
                xr[4] = xs[i][lb + 4];
                xr[5] = xs[i][lb + 5];
            }
            #pragma unroll
            for (int t = 0; t < 3; ++t) {
                float4 wv = *(const float4*)&wsh[i * 3 + t][ob];
                float wp[4] = {wv.x, wv.y, wv.z, wv.w};
                #pragma unroll
                for (int oo = 0; oo < 4; ++oo)
                    #pragma unroll
                    for (int ll = 0; ll < 4; ++ll)
                        acc[oo][ll] = fmaf(wp[oo], xr[ll * STRIDE + t], acc[oo][ll]);
            }
        }
    }

    // epilogue: +bias, BN (eval), LeakyReLU — same op order as reference
    float res[4][4];
    #pragma unroll
    for (int oo = 0; oo < 4; ++oo) {
        int o = o0 + ob + oo;
        float inv = 1.0f / sqrtf(vv[o] + EPS_BN);
        float sc  = gg[o] * inv;
        float mo = mm[o], beo = be[o], bo = bias[o];
        #pragma unroll
        for (int ll = 0; ll < 4; ++ll) {
            float y = acc[oo][ll] + bo;
            float t = (y - mo) * sc + beo;
            res[oo][ll] = t >= 0.0f ? t : SLOPE * t;
        }
    }
    if (!TRANS_OUT) {
        #pragma unroll
        for (int oo = 0; oo < 4; ++oo) {
            int o = o0 + ob + oo;
            float4 r4 = make_float4(res[oo][0], res[oo][1], res[oo][2], res[oo][3]);
            *(float4*)&out[((size_t)b * COUT + o) * LOUT + l0 + lb] = r4;
        }
    } else {
        // write transposed: f[(b*LOUT + l)*COUT + o]  (flat [N][D])
        #pragma unroll
        for (int ll = 0; ll < 4; ++ll) {
            int l = l0 + lb + ll;
            float4 r4 = make_float4(res[0][ll], res[1][ll], res[2][ll], res[3][ll]);
            *(float4*)&out[((size_t)(b * LOUT + l)) * COUT + o0 + ob] = r4;
        }
    }
}

// ---------- 32x32 LDS tile transpose: in[R][C] -> out[C][R] ----------
__global__ __launch_bounds__(256)
void transpose_kernel(const float* __restrict__ in, float* __restrict__ out,
                      int R, int C)
{
    __shared__ float t[32][33];
    int c0 = blockIdx.x * 32, r0 = blockIdx.y * 32;
    int x = threadIdx.x & 31, y = threadIdx.x >> 5;   // y in [0,8)
    #pragma unroll
    for (int k = 0; k < 4; ++k)
        t[y + k * 8][x] = in[(size_t)(r0 + y + k * 8) * C + c0 + x];
    __syncthreads();
    #pragma unroll
    for (int k = 0; k < 4; ++k)
        out[(size_t)(c0 + y + k * 8) * R + r0 + x] = t[x][y + k * 8];
}

// ---------- row sum-of-squares from transposed layout inT[D][N] ----------
__global__ __launch_bounds__(256)
void sumsq_kernel(const float* __restrict__ inT, float* __restrict__ outv,
                  int N, int D)
{
    int n = blockIdx.x * 256 + threadIdx.x;
    if (n >= N) return;
    float s = 0.0f;
    for (int d = 0; d < D; ++d) {
        float x = inT[(size_t)d * N + n];
        s = fmaf(x, x, s);
    }
    outv[n] = s;
}

// ---------- dist[n][k] = sf[n] + se[k] - 2 * <f_n, e_k> ----------
__global__ __launch_bounds__(256)
void dist_kernel(const float* __restrict__ fT, const float* __restrict__ eT,
                 const float* __restrict__ sf, const float* __restrict__ se,
                 float* __restrict__ dist)
{
    constexpr int N = 8192, K = 4096, D = 128;
    __shared__ __align__(16) float fs[D][64];
    __shared__ __align__(16) float es[D][64];
    const int tid = threadIdx.x;
    const int k0 = blockIdx.x * 64, n0 = blockIdx.y * 64;
    const int r = tid & 63, c0 = tid >> 6;

    for (int cc = 0; cc < 32; ++cc) {
        int d = c0 * 32 + cc;
        fs[d][r] = fT[(size_t)d * N + n0 + r];
        es[d][r] = eT[(size_t)d * K + k0 + r];
    }
    __syncthreads();

    const int nt = tid & 15, kt = tid >> 4;
    float acc[4][4] = {};
    #pragma unroll 4
    for (int d = 0; d < D; ++d) {
        float4 a  = *(const float4*)&fs[d][nt * 4];
        float4 bv = *(const float4*)&es[d][kt * 4];
        float ax[4] = {a.x, a.y, a.z, a.w};
        float bx[4] = {bv.x, bv.y, bv.z, bv.w};
        #pragma unroll
        for (int i = 0; i < 4; ++i)
            #pragma unroll
            for (int j = 0; j < 4; ++j)
                acc[i][j] = fmaf(ax[i], bx[j], acc[i][j]);
    }

    #pragma unroll
    for (int i = 0; i < 4; ++i) {
        int n = n0 + nt * 4 + i;
        float sfn = sf[n];
        float o0v = (sfn + se[k0 + kt * 4 + 0]) - 2.0f * acc[i][0];
        float o1v = (sfn + se[k0 + kt * 4 + 1]) - 2.0f * acc[i][1];
        float o2v = (sfn + se[k0 + kt * 4 + 2]) - 2.0f * acc[i][2];
        float o3v = (sfn + se[k0 + kt * 4 + 3]) - 2.0f * acc[i][3];
        float4 r4 = make_float4(o0v, o1v, o2v, o3v);
        *(float4*)&dist[(size_t)n * K + k0 + kt * 4] = r4;
    }
}

// ---------- argmin over each row of dist (first-index tie-break) ----------
__global__ __launch_bounds__(256)
void argmin_kernel(const float* __restrict__ dist, float* __restrict__ codes)
{
    constexpr int K = 4096;
    __shared__ float sv[256];
    __shared__ int   si[256];
    const int n = blockIdx.x;
    const float* row = dist + (size_t)n * K;
    float bv = 3.4e38f;
    int bi = 0;
    for (int k = threadIdx.x; k < K; k += 256) {
        float v = row[k];
        if (v < bv) { bv = v; bi = k; }   // ascending k => first occurrence kept
    }
    sv[threadIdx.x] = bv; si[threadIdx.x] = bi;
    __syncthreads();
    for (int s = 128; s > 0; s >>= 1) {
        if (threadIdx.x < s) {
            float v2 = sv[threadIdx.x + s]; int i2 = si[threadIdx.x + s];
            if (v2 < sv[threadIdx.x] ||
                (v2 == sv[threadIdx.x] && i2 < si[threadIdx.x])) {
                sv[threadIdx.x] = v2; si[threadIdx.x] = i2;
            }
        }
        __syncthreads();
    }
    if (threadIdx.x == 0) codes[n] = (float)si[0];
}

// ---------------------------------------------------------------
extern "C" void kernel_launch(void* const* d_in, const int* in_sizes, int n_in,
                              void* d_out, int out_size, void* d_ws, size_t ws_size,
                              hipStream_t stream)
{
    const float* x   = (const float*)d_in[0];
    const float* w1  = (const float*)d_in[1];
    const float* b1  = (const float*)d_in[2];
    const float* w2  = (const float*)d_in[3];
    const float* b2  = (const float*)d_in[4];
    const float* w3  = (const float*)d_in[5];
    const float* b3  = (const float*)d_in[6];
    const float* w4  = (const float*)d_in[7];
    const float* b4  = (const float*)d_in[8];
    const float* g1  = (const float*)d_in[9];
    const float* be1 = (const float*)d_in[10];
    const float* m1  = (const float*)d_in[11];
    const float* v1  = (const float*)d_in[12];
    const float* g2  = (const float*)d_in[13];
    const float* be2 = (const float*)d_in[14];
    const float* m2  = (const float*)d_in[15];
    const float* v2  = (const float*)d_in[16];
    const float* g3  = (const float*)d_in[17];
    const float* be3 = (const float*)d_in[18];
    const float* m3  = (const float*)d_in[19];
    const float* v3  = (const float*)d_in[20];
    const float* g4  = (const float*)d_in[21];
    const float* be4 = (const float*)d_in[22];
    const float* m4  = (const float*)d_in[23];
    const float* v4  = (const float*)d_in[24];
    const float* emb = (const float*)d_in[25];

    float* outf  = (float*)d_out;
    float* codes = outf;            // [8192] written as float
    float* dist  = outf + 8192;     // [8192][4096]

    // workspace layout (floats)
    float* ws  = (float*)d_ws;
    float* wT1 = ws;                  // 196608
    float* wT2 = ws + 196608;         // 393216
    float* wT3 = ws + 589824;         // 786432
    float* wT4 = ws + 1376256;        // 196608
    float* h3  = ws + 1572864;        // 4194304  [32][512][256]
    float* f   = ws + 5767168;        // 1048576  [8192][128]
    float* fT  = ws + 6815744;        // 1048576  [128][8192]
    float* eT  = ws + 7864320;        // 524288   [128][4096]
    float* sf  = ws + 8388608;        // 8192
    float* se  = ws + 8396800;        // 4096

    // h1/h2 live inside the dist output region (dead before dist is written)
    float* h1 = dist;                 // 8388608  [32][256][1024]
    float* h2 = dist + 8388608;       // 8388608  [32][512][512]

    // weight transforms
    wprep_kernel<<<768,  256, 0, stream>>>(w1, wT1, 256, 256);
    wprep_kernel<<<1536, 256, 0, stream>>>(w2, wT2, 256, 512);
    wprep_kernel<<<3072, 256, 0, stream>>>(w3, wT3, 512, 512);
    wprep_kernel<<<768,  256, 0, stream>>>(w4, wT4, 512, 128);

    // conv stack
    conv_bn_lrelu<256, 256, 2048, 2, false>
        <<<dim3(16, 4, 32), 256, 0, stream>>>(x,  wT1, b1, g1, be1, m1, v1, h1);
    conv_bn_lrelu<256, 512, 1024, 2, false>
        <<<dim3(8, 8, 32), 256, 0, stream>>>(h1, wT2, b2, g2, be2, m2, v2, h2);
    conv_bn_lrelu<512, 512, 512, 2, false>
        <<<dim3(4, 8, 32), 256, 0, stream>>>(h2, wT3, b3, g3, be3, m3, v3, h3);
    conv_bn_lrelu<512, 128, 256, 1, true>
        <<<dim3(4, 2, 32), 256, 0, stream>>>(h3, wT4, b4, g4, be4, m4, v4, f);

    // transposes + norms
    transpose_kernel<<<dim3(4, 256), 256, 0, stream>>>(f,   fT, 8192, 128);
    transpose_kernel<<<dim3(4, 128), 256, 0, stream>>>(emb, eT, 4096, 128);
    sumsq_kernel<<<32, 256, 0, stream>>>(fT, sf, 8192, 128);
    sumsq_kernel<<<16, 256, 0, stream>>>(eT, se, 4096, 128);

    // distance matrix + argmin
    dist_kernel<<<dim3(64, 128), 256, 0, stream>>>(fT, eT, sf, se, dist);
    argmin_kernel<<<8192, 256, 0, stream>>>(dist, codes);
}